// Round 1
// baseline (360.760 us; speedup 1.0000x reference)
//
#include <hip/hip_runtime.h>

typedef __bf16 bf16x8 __attribute__((ext_vector_type(8)));
typedef float f32x4 __attribute__((ext_vector_type(4)));

#define LOG2E 1.4426950408889634f

static __device__ __forceinline__ unsigned short f2bf(float f) {
  union { float f; unsigned int u; } c; c.f = f;
  return (unsigned short)((c.u + 0x7fffu + ((c.u >> 16) & 1u)) >> 16);
}

static __device__ __forceinline__ void gload16(const void* g, void* l) {
  __builtin_amdgcn_global_load_lds(
      (const __attribute__((address_space(1))) void*)g,
      (__attribute__((address_space(3))) void*)l, 16, 0, 0);
}

// ---------------- fp32 -> bf16 convert (vec4) ----------------
__global__ void cvt_kernel(const float* __restrict__ in,
                           unsigned short* __restrict__ out, int n4) {
  int i = blockIdx.x * 256 + threadIdx.x;
  if (i < n4) {
    float4 f = ((const float4*)in)[i];
    ushort4 o;
    o.x = f2bf(f.x); o.y = f2bf(f.y); o.z = f2bf(f.z); o.w = f2bf(f.w);
    ((ushort4*)out)[i] = o;
  }
}

// ---------------- QKV projection GEMM ----------------
// A = xb [4096 x 1024] bf16 (k contig), B = W[qkv] [1024 x 1024] (k contig)
// C columns map to (qkv, g, d); epilogue scatters into per-head [head][s][64].
__launch_bounds__(256, 2)
__global__ void qkv_gemm(const unsigned short* __restrict__ xb,
                         const unsigned short* __restrict__ wq,
                         const unsigned short* __restrict__ wk,
                         const unsigned short* __restrict__ wv,
                         const float* __restrict__ bq,
                         const float* __restrict__ bk,
                         const float* __restrict__ bv,
                         unsigned short* __restrict__ Qo,
                         unsigned short* __restrict__ Ko,
                         unsigned short* __restrict__ Vo) {
  __shared__ unsigned short As[128 * 32];
  __shared__ unsigned short Bs[128 * 32];
  const int m0 = blockIdx.x * 128;
  const int n0g = blockIdx.y * 128;     // 0..3071
  const int qkv = n0g >> 10;
  const int n0 = n0g & 1023;
  const unsigned short* W = (qkv == 0) ? wq : ((qkv == 1) ? wk : wv);
  const float* bias = (qkv == 0) ? bq : ((qkv == 1) ? bk : bv);
  unsigned short* OUT = (qkv == 0) ? Qo : ((qkv == 1) ? Ko : Vo);

  const int tid = threadIdx.x;
  const int lane = tid & 63;
  const int wid = tid >> 6;
  const int wm = (wid >> 1) * 64;
  const int wn = (wid & 1) * 64;
  const int lm = lane & 15;
  const int lq = lane >> 4;

  const int c0 = tid, c1 = 256 + tid;
  const int ar0 = c0 >> 2, aj0 = c0 & 3;
  const int ar1 = c1 >> 2, aj1 = c1 & 3;

  f32x4 acc[4][4] = {};

  for (int kk = 0; kk < 1024; kk += 32) {
    gload16(xb + (size_t)(m0 + ar0) * 1024 + kk + aj0 * 8, As + c0 * 8);
    gload16(xb + (size_t)(m0 + ar1) * 1024 + kk + aj1 * 8, As + c1 * 8);
    gload16(W + (size_t)(n0 + ar0) * 1024 + kk + aj0 * 8, Bs + c0 * 8);
    gload16(W + (size_t)(n0 + ar1) * 1024 + kk + aj1 * 8, Bs + c1 * 8);
    __syncthreads();
    bf16x8 af[4], bff[4];
#pragma unroll
    for (int mt = 0; mt < 4; ++mt)
      af[mt] = *(const bf16x8*)(As + (wm + mt * 16 + lm) * 32 + lq * 8);
#pragma unroll
    for (int nt = 0; nt < 4; ++nt)
      bff[nt] = *(const bf16x8*)(Bs + (wn + nt * 16 + lm) * 32 + lq * 8);
#pragma unroll
    for (int mt = 0; mt < 4; ++mt)
#pragma unroll
      for (int nt = 0; nt < 4; ++nt)
        acc[mt][nt] = __builtin_amdgcn_mfma_f32_16x16x32_bf16(
            af[mt], bff[nt], acc[mt][nt], 0, 0, 0);
    __syncthreads();
  }

  const float scale = (qkv == 0) ? 0.125f : 1.0f;  // fold 1/sqrt(64) into Q
#pragma unroll
  for (int nt = 0; nt < 4; ++nt) {
    const int col = n0 + wn + nt * 16 + lm;  // 0..1023 within this W
    const int g = col >> 8, d = col & 255;
    const int hpg = d >> 6, hd = d & 63;
    const float bb = bias[col];
#pragma unroll
    for (int mt = 0; mt < 4; ++mt) {
#pragma unroll
      for (int r = 0; r < 4; ++r) {
        const int srow = m0 + wm + mt * 16 + lq * 4 + r;  // 0..4095
        const int bidx = srow >> 11, s = srow & 2047;
        const int head = (bidx * 4 + g) * 4 + hpg;        // 0..31
        OUT[(size_t)head * 131072 + (size_t)s * 64 + hd] =
            f2bf((acc[mt][nt][r] + bb) * scale);
      }
    }
  }
}

// ---------------- V transpose: [head][2048][64] -> [head][64][2048] ----------
__global__ void vtrans(const unsigned short* __restrict__ V,
                       unsigned short* __restrict__ VT) {
  __shared__ unsigned short tile[64][65];
  const int head = blockIdx.y;
  const int kv0 = blockIdx.x * 64;
  const unsigned short* src = V + (size_t)head * 131072 + (size_t)kv0 * 64;
  unsigned short* dst = VT + (size_t)head * 131072 + kv0;
  const int tid = threadIdx.x;
#pragma unroll
  for (int i = 0; i < 16; ++i) {
    int e = i * 256 + tid;
    int r = e >> 6, c = e & 63;
    tile[r][c] = src[r * 64 + c];
  }
  __syncthreads();
#pragma unroll
  for (int i = 0; i < 16; ++i) {
    int e = i * 256 + tid;
    int r = e >> 6, c = e & 63;   // r = hd, c = kv-local
    dst[(size_t)r * 2048 + c] = tile[c][r];
  }
}

// ---------------- flash attention: 1 block = (head, 128-row Q tile) ---------
__launch_bounds__(256, 2)
__global__ void attn_kernel(const unsigned short* __restrict__ Q,
                            const unsigned short* __restrict__ K,
                            const unsigned short* __restrict__ VT,
                            unsigned short* __restrict__ ctx) {
  __shared__ unsigned short Ks[2][128][32];   // [hd-slab][kv][32]   16 KB
  __shared__ unsigned short Vs[4][64][32];    // [kv-slab][hd][32kv] 16 KB
  __shared__ unsigned short Ps[128 * 128];    // swizzled P; Q staging  32 KB

  const int head = blockIdx.y;
  const int q0 = blockIdx.x * 128;
  const int b = head >> 4;
  const int colbase = (head & 15) * 64;       // g*256 + hpg*64

  const unsigned short* Qh = Q + (size_t)head * 131072 + (size_t)q0 * 64;
  const unsigned short* Kh = K + (size_t)head * 131072;
  const unsigned short* Vh = VT + (size_t)head * 131072;

  const int tid = threadIdx.x;
  const int lane = tid & 63;
  const int w = tid >> 6;
  const int lm = lane & 15;
  const int lq = lane >> 4;
  const int wq0 = w * 32;                     // this wave's q rows

  // stage Q (slab layout, into Ps region) + K/V for iter 0
#pragma unroll
  for (int t = 0; t < 4; ++t) {
    int c = t * 256 + tid;
    int slab = c >> 9, r = (c >> 2) & 127, j = c & 3;
    gload16(Qh + (size_t)r * 64 + slab * 32 + j * 8, Ps + c * 8);
  }
#pragma unroll
  for (int t = 0; t < 4; ++t) {
    int c = t * 256 + tid;
    { int slab = c >> 9, r = (c >> 2) & 127, j = c & 3;
      gload16(Kh + (size_t)r * 64 + slab * 32 + j * 8, &Ks[0][0][0] + c * 8); }
    { int slab = c >> 8, r = (c >> 2) & 63, j = c & 3;
      gload16(Vh + (size_t)r * 2048 + slab * 32 + j * 8, &Vs[0][0][0] + c * 8); }
  }
  __syncthreads();

  bf16x8 qf[2][2];
#pragma unroll
  for (int mt = 0; mt < 2; ++mt)
#pragma unroll
    for (int ks = 0; ks < 2; ++ks)
      qf[mt][ks] = *(const bf16x8*)(Ps + ks * 4096 + (wq0 + mt * 16 + lm) * 32 + lq * 8);
  __syncthreads();   // Ps now reusable for P

  float m_run[2][4], l_run[2][4];
  f32x4 o_acc[2][4] = {};
#pragma unroll
  for (int mt = 0; mt < 2; ++mt)
#pragma unroll
    for (int r = 0; r < 4; ++r) { m_run[mt][r] = -3.0e38f; l_run[mt][r] = 0.f; }

  for (int it = 0; it < 16; ++it) {
    // ---- S = Q K^T ----
    f32x4 sacc[2][8] = {};
#pragma unroll
    for (int ks = 0; ks < 2; ++ks) {
      bf16x8 kf[8];
#pragma unroll
      for (int nt = 0; nt < 8; ++nt)
        kf[nt] = *(const bf16x8*)(&Ks[ks][0][0] + (nt * 16 + lm) * 32 + lq * 8);
#pragma unroll
      for (int mt = 0; mt < 2; ++mt)
#pragma unroll
        for (int nt = 0; nt < 8; ++nt)
          sacc[mt][nt] = __builtin_amdgcn_mfma_f32_16x16x32_bf16(
              qf[mt][ks], kf[nt], sacc[mt][nt], 0, 0, 0);
    }
    // ---- online softmax (wave-private rows) ----
#pragma unroll
    for (int mt = 0; mt < 2; ++mt) {
      float tmax[4];
#pragma unroll
      for (int r = 0; r < 4; ++r) {
        float v = sacc[mt][0][r];
#pragma unroll
        for (int nt = 1; nt < 8; ++nt) v = fmaxf(v, sacc[mt][nt][r]);
        tmax[r] = v;
      }
#pragma unroll
      for (int off = 1; off < 16; off <<= 1)
#pragma unroll
        for (int r = 0; r < 4; ++r)
          tmax[r] = fmaxf(tmax[r], __shfl_xor(tmax[r], off, 64));
      float mnew[4], alpha[4], psum[4];
#pragma unroll
      for (int r = 0; r < 4; ++r) {
        mnew[r] = fmaxf(m_run[mt][r], tmax[r]);
        alpha[r] = exp2f((m_run[mt][r] - mnew[r]) * LOG2E);
        psum[r] = 0.f;
        m_run[mt][r] = mnew[r];
      }
#pragma unroll
      for (int nt = 0; nt < 8; ++nt) {
        const int kv = nt * 16 + lm;
        const int jbase = kv >> 3;
        const int kvlow = kv & 7;
#pragma unroll
        for (int r = 0; r < 4; ++r) {
          float p = exp2f((sacc[mt][nt][r] - mnew[r]) * LOG2E);
          psum[r] += p;
          int q = wq0 + mt * 16 + lq * 4 + r;
          int j = jbase ^ (q & 15);
          Ps[q * 128 + j * 8 + kvlow] = f2bf(p);
        }
      }
#pragma unroll
      for (int off = 1; off < 16; off <<= 1)
#pragma unroll
        for (int r = 0; r < 4; ++r)
          psum[r] += __shfl_xor(psum[r], off, 64);
#pragma unroll
      for (int r = 0; r < 4; ++r)
        l_run[mt][r] = l_run[mt][r] * alpha[r] + psum[r];
#pragma unroll
      for (int nt = 0; nt < 4; ++nt)
#pragma unroll
        for (int r = 0; r < 4; ++r)
          o_acc[mt][nt][r] *= alpha[r];
    }
    // ---- O += P V ----
#pragma unroll
    for (int ks = 0; ks < 4; ++ks) {
      bf16x8 pf[2], vf[4];
#pragma unroll
      for (int mt = 0; mt < 2; ++mt) {
        int q = wq0 + mt * 16 + lm;
        int j = (ks * 4 + lq) ^ (q & 15);
        pf[mt] = *(const bf16x8*)(Ps + q * 128 + j * 8);
      }
#pragma unroll
      for (int nt = 0; nt < 4; ++nt)
        vf[nt] = *(const bf16x8*)(&Vs[ks][0][0] + (nt * 16 + lm) * 32 + lq * 8);
#pragma unroll
      for (int mt = 0; mt < 2; ++mt)
#pragma unroll
        for (int nt = 0; nt < 4; ++nt)
          o_acc[mt][nt] = __builtin_amdgcn_mfma_f32_16x16x32_bf16(
              pf[mt], vf[nt], o_acc[mt][nt], 0, 0, 0);
    }
    __syncthreads();
    if (it < 15) {
      const int kv0 = (it + 1) * 128;
#pragma unroll
      for (int t = 0; t < 4; ++t) {
        int c = t * 256 + tid;
        { int slab = c >> 9, r = (c >> 2) & 127, j = c & 3;
          gload16(Kh + (size_t)(kv0 + r) * 64 + slab * 32 + j * 8,
                  &Ks[0][0][0] + c * 8); }
        { int slab = c >> 8, r = (c >> 2) & 63, j = c & 3;
          gload16(Vh + (size_t)r * 2048 + kv0 + slab * 32 + j * 8,
                  &Vs[0][0][0] + c * 8); }
      }
      __syncthreads();
    }
  }
  // ---- epilogue: normalize, write ctx bf16 [b*2048+s][g*256+hpg*64+hd] ----
#pragma unroll
  for (int mt = 0; mt < 2; ++mt) {
    float inv[4];
#pragma unroll
    for (int r = 0; r < 4; ++r) inv[r] = 1.0f / l_run[mt][r];
#pragma unroll
    for (int nt = 0; nt < 4; ++nt) {
#pragma unroll
      for (int r = 0; r < 4; ++r) {
        int s = q0 + wq0 + mt * 16 + lq * 4 + r;
        int hd = nt * 16 + lm;
        ctx[(size_t)(b * 2048 + s) * 1024 + colbase + hd] =
            f2bf(o_acc[mt][nt][r] * inv[r]);
      }
    }
  }
}

// ---------------- output projection GEMM + bias -> fp32 out ----------------
__launch_bounds__(256, 2)
__global__ void out_gemm(const unsigned short* __restrict__ A,   // ctx [4096][1024]
                         const unsigned short* __restrict__ Wb,  // Wo   [1024][1024]
                         const float* __restrict__ bo,
                         float* __restrict__ out) {
  __shared__ unsigned short As[128 * 32];
  __shared__ unsigned short Bs[128 * 32];
  const int m0 = blockIdx.x * 128;
  const int n0 = blockIdx.y * 128;

  const int tid = threadIdx.x;
  const int lane = tid & 63;
  const int wid = tid >> 6;
  const int wm = (wid >> 1) * 64;
  const int wn = (wid & 1) * 64;
  const int lm = lane & 15;
  const int lq = lane >> 4;

  const int c0 = tid, c1 = 256 + tid;
  const int ar0 = c0 >> 2, aj0 = c0 & 3;
  const int ar1 = c1 >> 2, aj1 = c1 & 3;

  f32x4 acc[4][4] = {};

  for (int kk = 0; kk < 1024; kk += 32) {
    gload16(A + (size_t)(m0 + ar0) * 1024 + kk + aj0 * 8, As + c0 * 8);
    gload16(A + (size_t)(m0 + ar1) * 1024 + kk + aj1 * 8, As + c1 * 8);
    gload16(Wb + (size_t)(n0 + ar0) * 1024 + kk + aj0 * 8, Bs + c0 * 8);
    gload16(Wb + (size_t)(n0 + ar1) * 1024 + kk + aj1 * 8, Bs + c1 * 8);
    __syncthreads();
    bf16x8 af[4], bff[4];
#pragma unroll
    for (int mt = 0; mt < 4; ++mt)
      af[mt] = *(const bf16x8*)(As + (wm + mt * 16 + lm) * 32 + lq * 8);
#pragma unroll
    for (int nt = 0; nt < 4; ++nt)
      bff[nt] = *(const bf16x8*)(Bs + (wn + nt * 16 + lm) * 32 + lq * 8);
#pragma unroll
    for (int mt = 0; mt < 4; ++mt)
#pragma unroll
      for (int nt = 0; nt < 4; ++nt)
        acc[mt][nt] = __builtin_amdgcn_mfma_f32_16x16x32_bf16(
            af[mt], bff[nt], acc[mt][nt], 0, 0, 0);
    __syncthreads();
  }

#pragma unroll
  for (int nt = 0; nt < 4; ++nt) {
    const int col = n0 + wn + nt * 16 + lm;
    const float bb = bo[col];
#pragma unroll
    for (int mt = 0; mt < 4; ++mt) {
#pragma unroll
      for (int r = 0; r < 4; ++r) {
        const int row = m0 + wm + mt * 16 + lq * 4 + r;
        out[(size_t)row * 1024 + col] = acc[mt][nt][r] + bb;
      }
    }
  }
}

extern "C" void kernel_launch(void* const* d_in, const int* in_sizes, int n_in,
                              void* d_out, int out_size, void* d_ws, size_t ws_size,
                              hipStream_t stream) {
  const float* x  = (const float*)d_in[0];
  const float* Wq = (const float*)d_in[1];
  const float* bq = (const float*)d_in[2];
  const float* Wk = (const float*)d_in[3];
  const float* bk = (const float*)d_in[4];
  const float* Wv = (const float*)d_in[5];
  const float* bv = (const float*)d_in[6];
  const float* Wo = (const float*)d_in[7];
  const float* bo = (const float*)d_in[8];
  float* out = (float*)d_out;

  char* ws = (char*)d_ws;
  // workspace layout (bytes)
  unsigned short* xb  = (unsigned short*)(ws + 0);          //  8 MB  x bf16
  unsigned short* wqb = (unsigned short*)(ws + 8388608);    //  2 MB
  unsigned short* wkb = (unsigned short*)(ws + 10485760);   //  2 MB
  unsigned short* wvb = (unsigned short*)(ws + 12582912);   //  2 MB
  unsigned short* wob = (unsigned short*)(ws + 14680064);   //  2 MB
  unsigned short* Qb  = (unsigned short*)(ws + 16777216);   //  8 MB [32][2048][64]
  unsigned short* Kb  = (unsigned short*)(ws + 25165824);   //  8 MB
  unsigned short* Vb  = (unsigned short*)(ws + 33554432);   //  8 MB
  unsigned short* VTb = (unsigned short*)(ws + 41943040);   //  8 MB [32][64][2048]
  unsigned short* ctxb= (unsigned short*)(ws + 50331648);   //  8 MB [4096][1024]
  if (ws_size < 58720256) return;

  cvt_kernel<<<4096, 256, 0, stream>>>(x,  xb,  1048576);
  cvt_kernel<<<1024, 256, 0, stream>>>(Wq, wqb, 262144);
  cvt_kernel<<<1024, 256, 0, stream>>>(Wk, wkb, 262144);
  cvt_kernel<<<1024, 256, 0, stream>>>(Wv, wvb, 262144);
  cvt_kernel<<<1024, 256, 0, stream>>>(Wo, wob, 262144);

  qkv_gemm<<<dim3(32, 24), 256, 0, stream>>>(xb, wqb, wkb, wvb, bq, bk, bv,
                                             Qb, Kb, Vb);
  vtrans<<<dim3(32, 32), 256, 0, stream>>>(Vb, VTb);
  attn_kernel<<<dim3(16, 32), 256, 0, stream>>>(Qb, Kb, VTb, ctxb);
  out_gemm<<<dim3(32, 8), 256, 0, stream>>>(ctxb, wob, bo, out);
}

// Round 2
// 205.916 us; speedup vs baseline: 1.7520x; 1.7520x over previous
//
#include <hip/hip_runtime.h>

typedef __bf16 bf16x8 __attribute__((ext_vector_type(8)));
typedef __bf16 bf16x4 __attribute__((ext_vector_type(4)));
typedef short short4v __attribute__((ext_vector_type(4)));
typedef float f32x4 __attribute__((ext_vector_type(4)));

#define LOG2E 1.4426950408889634f

static __device__ __forceinline__ unsigned short f2bf(float f) {
  union { float f; unsigned int u; } c; c.f = f;
  return (unsigned short)((c.u + 0x7fffu + ((c.u >> 16) & 1u)) >> 16);
}

static __device__ __forceinline__ void gload16(const void* g, void* l) {
  __builtin_amdgcn_global_load_lds(
      (const __attribute__((address_space(1))) void*)g,
      (__attribute__((address_space(3))) void*)l, 16, 0, 0);
}

static __device__ __forceinline__ float expfast(float x) {
#if __has_builtin(__builtin_amdgcn_exp2f)
  return __builtin_amdgcn_exp2f(x * LOG2E);
#else
  return exp2f(x * LOG2E);
#endif
}

#if __has_builtin(__builtin_amdgcn_mfma_f32_16x16x16bf16_1k)
#define MFMA16_FALLBACK 0
static __device__ __forceinline__ f32x4 mfma16(bf16x4 a, bf16x4 b, f32x4 c) {
  return __builtin_amdgcn_mfma_f32_16x16x16bf16_1k(
      __builtin_bit_cast(short4v, a), __builtin_bit_cast(short4v, b), c, 0, 0, 0);
}
#else
#define MFMA16_FALLBACK 1
static __device__ __forceinline__ f32x4 mfma16(bf16x4 a, bf16x4 b, f32x4 c) {
  f32x4 d;
  asm("s_nop 1\n\tv_mfma_f32_16x16x16_bf16 %0, %1, %2, %3"
      : "=v"(d) : "v"(a), "v"(b), "v"(c));
  return d;
}
#endif

// ---------------- fp32 -> bf16 convert (vec4) ----------------
__global__ void cvt_kernel(const float* __restrict__ in,
                           unsigned short* __restrict__ out, int n4) {
  int i = blockIdx.x * 256 + threadIdx.x;
  if (i < n4) {
    float4 f = ((const float4*)in)[i];
    ushort4 o;
    o.x = f2bf(f.x); o.y = f2bf(f.y); o.z = f2bf(f.z); o.w = f2bf(f.w);
    ((ushort4*)out)[i] = o;
  }
}

// ---------------- QKV projection GEMM ----------------
__launch_bounds__(256, 2)
__global__ void qkv_gemm(const unsigned short* __restrict__ xb,
                         const unsigned short* __restrict__ wq,
                         const unsigned short* __restrict__ wk,
                         const unsigned short* __restrict__ wv,
                         const float* __restrict__ bq,
                         const float* __restrict__ bk,
                         const float* __restrict__ bv,
                         unsigned short* __restrict__ Qo,
                         unsigned short* __restrict__ Ko,
                         unsigned short* __restrict__ Vo) {
  __shared__ unsigned short As[128 * 32];
  __shared__ unsigned short Bs[128 * 32];
  const int m0 = blockIdx.x * 128;
  const int n0g = blockIdx.y * 128;
  const int qkv = n0g >> 10;
  const int n0 = n0g & 1023;
  const unsigned short* W = (qkv == 0) ? wq : ((qkv == 1) ? wk : wv);
  const float* bias = (qkv == 0) ? bq : ((qkv == 1) ? bk : bv);
  unsigned short* OUT = (qkv == 0) ? Qo : ((qkv == 1) ? Ko : Vo);

  const int tid = threadIdx.x;
  const int lane = tid & 63;
  const int wid = tid >> 6;
  const int wm = (wid >> 1) * 64;
  const int wn = (wid & 1) * 64;
  const int lm = lane & 15;
  const int lq = lane >> 4;

  const int c0 = tid, c1 = 256 + tid;
  const int ar0 = c0 >> 2, aj0 = c0 & 3;
  const int ar1 = c1 >> 2, aj1 = c1 & 3;

  f32x4 acc[4][4] = {};

  for (int kk = 0; kk < 1024; kk += 32) {
    gload16(xb + (size_t)(m0 + ar0) * 1024 + kk + aj0 * 8, As + c0 * 8);
    gload16(xb + (size_t)(m0 + ar1) * 1024 + kk + aj1 * 8, As + c1 * 8);
    gload16(W + (size_t)(n0 + ar0) * 1024 + kk + aj0 * 8, Bs + c0 * 8);
    gload16(W + (size_t)(n0 + ar1) * 1024 + kk + aj1 * 8, Bs + c1 * 8);
    __syncthreads();
    bf16x8 af[4], bff[4];
#pragma unroll
    for (int mt = 0; mt < 4; ++mt)
      af[mt] = *(const bf16x8*)(As + (wm + mt * 16 + lm) * 32 + lq * 8);
#pragma unroll
    for (int nt = 0; nt < 4; ++nt)
      bff[nt] = *(const bf16x8*)(Bs + (wn + nt * 16 + lm) * 32 + lq * 8);
#pragma unroll
    for (int mt = 0; mt < 4; ++mt)
#pragma unroll
      for (int nt = 0; nt < 4; ++nt)
        acc[mt][nt] = __builtin_amdgcn_mfma_f32_16x16x32_bf16(
            af[mt], bff[nt], acc[mt][nt], 0, 0, 0);
    __syncthreads();
  }

  const float scale = (qkv == 0) ? 0.125f : 1.0f;
#pragma unroll
  for (int nt = 0; nt < 4; ++nt) {
    const int col = n0 + wn + nt * 16 + lm;
    const int g = col >> 8, d = col & 255;
    const int hpg = d >> 6, hd = d & 63;
    const float bb = bias[col];
#pragma unroll
    for (int mt = 0; mt < 4; ++mt) {
#pragma unroll
      for (int r = 0; r < 4; ++r) {
        const int srow = m0 + wm + mt * 16 + lq * 4 + r;
        const int bidx = srow >> 11, s = srow & 2047;
        const int head = (bidx * 4 + g) * 4 + hpg;
        OUT[(size_t)head * 131072 + (size_t)s * 64 + hd] =
            f2bf((acc[mt][nt][r] + bb) * scale);
      }
    }
  }
}

// ---------------- V transpose: [head][2048][64] -> [head][64][2048] ----------
__global__ void vtrans(const unsigned short* __restrict__ V,
                       unsigned short* __restrict__ VT) {
  __shared__ unsigned short tile[64][65];
  const int head = blockIdx.y;
  const int kv0 = blockIdx.x * 64;
  const unsigned short* src = V + (size_t)head * 131072 + (size_t)kv0 * 64;
  unsigned short* dst = VT + (size_t)head * 131072 + kv0;
  const int tid = threadIdx.x;
#pragma unroll
  for (int i = 0; i < 16; ++i) {
    int e = i * 256 + tid;
    int r = e >> 6, c = e & 63;
    tile[r][c] = src[r * 64 + c];
  }
  __syncthreads();
#pragma unroll
  for (int i = 0; i < 16; ++i) {
    int e = i * 256 + tid;
    int r = e >> 6, c = e & 63;
    dst[(size_t)r * 2048 + c] = tile[c][r];
  }
}

// ---- double-buffered K/V staging with 16B-granular XOR swizzle ----
static __device__ __forceinline__ void stage_kv(
    const unsigned short* Kh, const unsigned short* Vh, int kv0,
    unsigned short* ksl, unsigned short* vsl, int tid) {
#pragma unroll
  for (int t = 0; t < 4; ++t) {
    int i = t * 256 + tid;
    int slab = i >> 9, kv = (i >> 2) & 127, tp = i & 3;
    int tc = tp ^ ((kv >> 1) & 3);
    gload16(Kh + (size_t)(kv0 + kv) * 64 + slab * 32 + tc * 8, ksl + (size_t)i * 8);
  }
#pragma unroll
  for (int t = 0; t < 4; ++t) {
    int i = t * 256 + tid;
    int hd = i >> 4, tp = i & 15;
    int tc = tp ^ ((hd >> 1) & 7);
    gload16(Vh + (size_t)hd * 2048 + kv0 + tc * 8, vsl + (size_t)i * 8);
  }
}

// ---------------- attention v2: S^T trick, no P LDS, dbuf K/V ----------------
// Block: 256 thr (4 waves), wave w owns q rows [q0+w*32, +32) as 2 n-tiles.
// S^T = K·Q^T  (M=kv, N=q, 16x16x32): C-layout => lane(quad,lm) reg r holds
// S^T[kv=16mt+4quad+r][q=lm] — exactly the B-operand layout (k=4quad+j) of
// mfma_16x16x16, so P^T feeds O^T = V^T·P^T with zero cross-lane traffic.
__launch_bounds__(256, 2)
__global__ void attn_kernel(const unsigned short* __restrict__ Q,
                            const unsigned short* __restrict__ K,
                            const unsigned short* __restrict__ VT,
                            unsigned short* __restrict__ ctx) {
  __shared__ unsigned short Ks[2][8192];   // [buf][slab2][kv128][32hd] 16KB/buf
  __shared__ unsigned short Vs[2][8192];   // [buf][hd64][kv128]      16KB/buf

  const int head = blockIdx.y;
  const int q0 = blockIdx.x * 128;
  const int b = head >> 4;
  const int colbase = (head & 15) * 64;

  const unsigned short* Kh = K + (size_t)head * 131072;
  const unsigned short* Vh = VT + (size_t)head * 131072;

  const int tid = threadIdx.x;
  const int lane = tid & 63;
  const int w = tid >> 6;
  const int lm = lane & 15;
  const int quad = lane >> 4;

  // Q B-fragments straight from global (once): qf[c][nt], hd = 32c+8*quad+j
  bf16x8 qf[2][2];
#pragma unroll
  for (int nt = 0; nt < 2; ++nt) {
    const size_t qrow = (size_t)(q0 + w * 32 + nt * 16 + lm);
#pragma unroll
    for (int c = 0; c < 2; ++c)
      qf[c][nt] = *(const bf16x8*)(Q + (size_t)head * 131072 + qrow * 64 +
                                   c * 32 + quad * 8);
  }

  stage_kv(Kh, Vh, 0, Ks[0], Vs[0], tid);
  __syncthreads();

  float psum[2] = {0.f, 0.f};
  f32x4 oacc[4][2] = {};
  const int kchunk = (quad ^ ((lm >> 1) & 3)) * 8;   // swizzled 16B pos (shorts)

  for (int it = 0; it < 16; ++it) {
    const int buf = it & 1;
    if (it < 15)
      stage_kv(Kh, Vh, (it + 1) * 128, Ks[buf ^ 1], Vs[buf ^ 1], tid);

    const unsigned short* kb = Ks[buf];
    const unsigned short* vb = Vs[buf];

#pragma unroll
    for (int mt = 0; mt < 8; ++mt) {
      f32x4 s0 = {}, s1 = {};
#pragma unroll
      for (int c = 0; c < 2; ++c) {
        bf16x8 kf = *(const bf16x8*)(kb + c * 4096 + (mt * 16 + lm) * 32 + kchunk);
        s0 = __builtin_amdgcn_mfma_f32_16x16x32_bf16(kf, qf[c][0], s0, 0, 0, 0);
        s1 = __builtin_amdgcn_mfma_f32_16x16x32_bf16(kf, qf[c][1], s1, 0, 0, 0);
      }
      bf16x4 pf[2];
#pragma unroll
      for (int nt = 0; nt < 2; ++nt) {
        const f32x4 s = nt ? s1 : s0;
        float e0 = expfast(s[0]), e1 = expfast(s[1]);
        float e2 = expfast(s[2]), e3 = expfast(s[3]);
        psum[nt] += (e0 + e1) + (e2 + e3);
        bf16x4 t;
        t[0] = (__bf16)e0; t[1] = (__bf16)e1; t[2] = (__bf16)e2; t[3] = (__bf16)e3;
        pf[nt] = t;
      }
#pragma unroll
      for (int hm = 0; hm < 4; ++hm) {
        bf16x4 vf = *(const bf16x4*)(vb + (hm * 16 + lm) * 128 +
                                     (((mt * 4 + quad) ^ (lm & 14)) * 4));
        oacc[hm][0] = mfma16(vf, pf[0], oacc[hm][0]);
        oacc[hm][1] = mfma16(vf, pf[1], oacc[hm][1]);
      }
    }
    __syncthreads();
  }

#if MFMA16_FALLBACK
  asm volatile("s_nop 7\n\ts_nop 7");
#endif
#pragma unroll
  for (int nt = 0; nt < 2; ++nt) {
    float p = psum[nt];
    p += __shfl_xor(p, 16, 64);
    p += __shfl_xor(p, 32, 64);
    const float inv = 1.0f / p;
    const size_t row = (size_t)(b * 2048 + q0 + w * 32 + nt * 16 + lm);
#pragma unroll
    for (int hm = 0; hm < 4; ++hm) {
      ushort4 o;
      o.x = f2bf(oacc[hm][nt][0] * inv);
      o.y = f2bf(oacc[hm][nt][1] * inv);
      o.z = f2bf(oacc[hm][nt][2] * inv);
      o.w = f2bf(oacc[hm][nt][3] * inv);
      *(ushort4*)(ctx + row * 1024 + colbase + hm * 16 + quad * 4) = o;
    }
  }
}

// ---------------- output projection GEMM + bias -> fp32 out ----------------
__launch_bounds__(256, 2)
__global__ void out_gemm(const unsigned short* __restrict__ A,
                         const unsigned short* __restrict__ Wb,
                         const float* __restrict__ bo,
                         float* __restrict__ out) {
  __shared__ unsigned short As[128 * 32];
  __shared__ unsigned short Bs[128 * 32];
  const int m0 = blockIdx.x * 128;
  const int n0 = blockIdx.y * 128;

  const int tid = threadIdx.x;
  const int lane = tid & 63;
  const int wid = tid >> 6;
  const int wm = (wid >> 1) * 64;
  const int wn = (wid & 1) * 64;
  const int lm = lane & 15;
  const int lq = lane >> 4;

  const int c0 = tid, c1 = 256 + tid;
  const int ar0 = c0 >> 2, aj0 = c0 & 3;
  const int ar1 = c1 >> 2, aj1 = c1 & 3;

  f32x4 acc[4][4] = {};

  for (int kk = 0; kk < 1024; kk += 32) {
    gload16(A + (size_t)(m0 + ar0) * 1024 + kk + aj0 * 8, As + c0 * 8);
    gload16(A + (size_t)(m0 + ar1) * 1024 + kk + aj1 * 8, As + c1 * 8);
    gload16(Wb + (size_t)(n0 + ar0) * 1024 + kk + aj0 * 8, Bs + c0 * 8);
    gload16(Wb + (size_t)(n0 + ar1) * 1024 + kk + aj1 * 8, Bs + c1 * 8);
    __syncthreads();
    bf16x8 af[4], bff[4];
#pragma unroll
    for (int mt = 0; mt < 4; ++mt)
      af[mt] = *(const bf16x8*)(As + (wm + mt * 16 + lm) * 32 + lq * 8);
#pragma unroll
    for (int nt = 0; nt < 4; ++nt)
      bff[nt] = *(const bf16x8*)(Bs + (wn + nt * 16 + lm) * 32 + lq * 8);
#pragma unroll
    for (int mt = 0; mt < 4; ++mt)
#pragma unroll
      for (int nt = 0; nt < 4; ++nt)
        acc[mt][nt] = __builtin_amdgcn_mfma_f32_16x16x32_bf16(
            af[mt], bff[nt], acc[mt][nt], 0, 0, 0);
    __syncthreads();
  }

#pragma unroll
  for (int nt = 0; nt < 4; ++nt) {
    const int col = n0 + wn + nt * 16 + lm;
    const float bb = bo[col];
#pragma unroll
    for (int mt = 0; mt < 4; ++mt) {
#pragma unroll
      for (int r = 0; r < 4; ++r) {
        const int row = m0 + wm + mt * 16 + lq * 4 + r;
        out[(size_t)row * 1024 + col] = acc[mt][nt][r] + bb;
      }
    }
  }
}

extern "C" void kernel_launch(void* const* d_in, const int* in_sizes, int n_in,
                              void* d_out, int out_size, void* d_ws, size_t ws_size,
                              hipStream_t stream) {
  const float* x  = (const float*)d_in[0];
  const float* Wq = (const float*)d_in[1];
  const float* bq = (const float*)d_in[2];
  const float* Wk = (const float*)d_in[3];
  const float* bk = (const float*)d_in[4];
  const float* Wv = (const float*)d_in[5];
  const float* bv = (const float*)d_in[6];
  const float* Wo = (const float*)d_in[7];
  const float* bo = (const float*)d_in[8];
  float* out = (float*)d_out;

  char* ws = (char*)d_ws;
  unsigned short* xb  = (unsigned short*)(ws + 0);
  unsigned short* wqb = (unsigned short*)(ws + 8388608);
  unsigned short* wkb = (unsigned short*)(ws + 10485760);
  unsigned short* wvb = (unsigned short*)(ws + 12582912);
  unsigned short* wob = (unsigned short*)(ws + 14680064);
  unsigned short* Qb  = (unsigned short*)(ws + 16777216);
  unsigned short* Kb  = (unsigned short*)(ws + 25165824);
  unsigned short* Vb  = (unsigned short*)(ws + 33554432);
  unsigned short* VTb = (unsigned short*)(ws + 41943040);
  unsigned short* ctxb= (unsigned short*)(ws + 50331648);
  if (ws_size < 58720256) return;

  cvt_kernel<<<4096, 256, 0, stream>>>(x,  xb,  1048576);
  cvt_kernel<<<1024, 256, 0, stream>>>(Wq, wqb, 262144);
  cvt_kernel<<<1024, 256, 0, stream>>>(Wk, wkb, 262144);
  cvt_kernel<<<1024, 256, 0, stream>>>(Wv, wvb, 262144);
  cvt_kernel<<<1024, 256, 0, stream>>>(Wo, wob, 262144);

  qkv_gemm<<<dim3(32, 24), 256, 0, stream>>>(xb, wqb, wkb, wvb, bq, bk, bv,
                                             Qb, Kb, Vb);
  vtrans<<<dim3(32, 32), 256, 0, stream>>>(Vb, VTb);
  attn_kernel<<<dim3(16, 32), 256, 0, stream>>>(Qb, Kb, VTb, ctxb);
  out_gemm<<<dim3(32, 8), 256, 0, stream>>>(ctxb, wob, bo, out);
}

// Round 3
// 198.504 us; speedup vs baseline: 1.8174x; 1.0373x over previous
//
#include <hip/hip_runtime.h>

typedef __bf16 bf16x8 __attribute__((ext_vector_type(8)));
typedef __bf16 bf16x4 __attribute__((ext_vector_type(4)));
typedef short short4v __attribute__((ext_vector_type(4)));
typedef float f32x4 __attribute__((ext_vector_type(4)));

#define LOG2E 1.4426950408889634f

static __device__ __forceinline__ unsigned short f2bf(float f) {
  union { float f; unsigned int u; } c; c.f = f;
  return (unsigned short)((c.u + 0x7fffu + ((c.u >> 16) & 1u)) >> 16);
}

static __device__ __forceinline__ void gload16(const void* g, void* l) {
  __builtin_amdgcn_global_load_lds(
      (const __attribute__((address_space(1))) void*)g,
      (__attribute__((address_space(3))) void*)l, 16, 0, 0);
}

static __device__ __forceinline__ float expfast(float x) {
#if __has_builtin(__builtin_amdgcn_exp2f)
  return __builtin_amdgcn_exp2f(x * LOG2E);
#else
  return exp2f(x * LOG2E);
#endif
}

#if __has_builtin(__builtin_amdgcn_mfma_f32_16x16x16bf16_1k)
#define MFMA16_FALLBACK 0
static __device__ __forceinline__ f32x4 mfma16(bf16x4 a, bf16x4 b, f32x4 c) {
  return __builtin_amdgcn_mfma_f32_16x16x16bf16_1k(
      __builtin_bit_cast(short4v, a), __builtin_bit_cast(short4v, b), c, 0, 0, 0);
}
#else
#define MFMA16_FALLBACK 1
static __device__ __forceinline__ f32x4 mfma16(bf16x4 a, bf16x4 b, f32x4 c) {
  f32x4 d;
  asm("s_nop 1\n\tv_mfma_f32_16x16x16_bf16 %0, %1, %2, %3"
      : "=v"(d) : "v"(a), "v"(b), "v"(c));
  return d;
}
#endif

// ---------------- fused fp32 -> bf16 convert for x + 4 weights ----------------
// dst is linear in ws: [xb 1048576 grp][wq 262144][wk][wv][wo]
__global__ void cvt_all(const float* __restrict__ x,
                        const float* __restrict__ Wq,
                        const float* __restrict__ Wk,
                        const float* __restrict__ Wv,
                        const float* __restrict__ Wo,
                        ushort4* __restrict__ dst) {
  int i = blockIdx.x * 256 + threadIdx.x;
  const float* src;
  int off;
  if (i < 1048576) {
    src = x; off = i;
  } else {
    int t = (i - 1048576) >> 18;
    off = (i - 1048576) & 262143;
    src = (t == 0) ? Wq : (t == 1) ? Wk : (t == 2) ? Wv : Wo;
  }
  float4 f = ((const float4*)src)[off];
  ushort4 o;
  o.x = f2bf(f.x); o.y = f2bf(f.y); o.z = f2bf(f.z); o.w = f2bf(f.w);
  dst[i] = o;
}

// ---------------- QKV projection GEMM ----------------
// For Q/K: compute C^T = W·x^T  (A=W rows=d, B=x rows=s) so 4 consecutive hd
// live in regs -> ushort4 stores into [head][s][64].
// For V: keep C = x·W^T (s in regs) and write V TRANSPOSED [head][hd][s]
// with ushort4 packing 4 consecutive s. vtrans kernel eliminated.
__launch_bounds__(256, 2)
__global__ void qkv_gemm(const unsigned short* __restrict__ xb,
                         const unsigned short* __restrict__ wq,
                         const unsigned short* __restrict__ wk,
                         const unsigned short* __restrict__ wv,
                         const float* __restrict__ bq,
                         const float* __restrict__ bk,
                         const float* __restrict__ bv,
                         unsigned short* __restrict__ Qo,
                         unsigned short* __restrict__ Ko,
                         unsigned short* __restrict__ VTo) {
  __shared__ unsigned short As[128 * 32];
  __shared__ unsigned short Bs[128 * 32];
  const int s0 = blockIdx.x * 128;
  const int n0g = blockIdx.y * 128;     // 0..3071
  const int qkv = n0g >> 10;
  const int d0 = n0g & 1023;
  const unsigned short* W = (qkv == 0) ? wq : ((qkv == 1) ? wk : wv);
  const float* bias = (qkv == 0) ? bq : ((qkv == 1) ? bk : bv);

  // operand roles: A-> m-dim (ends up in regs), B-> n-dim (ends up in lanes)
  const unsigned short* Aptr; const unsigned short* Bptr;
  int Aoff, Boff;
  if (qkv < 2) { Aptr = W;  Aoff = d0; Bptr = xb; Boff = s0; }
  else         { Aptr = xb; Aoff = s0; Bptr = W;  Boff = d0; }

  const int tid = threadIdx.x;
  const int lane = tid & 63;
  const int wid = tid >> 6;
  const int wm = (wid >> 1) * 64;
  const int wn = (wid & 1) * 64;
  const int lm = lane & 15;
  const int quad = lane >> 4;

  const int c0 = tid, c1 = 256 + tid;
  const int ar0 = c0 >> 2, aj0 = c0 & 3;
  const int ar1 = c1 >> 2, aj1 = c1 & 3;

  f32x4 acc[4][4] = {};

  for (int kk = 0; kk < 1024; kk += 32) {
    gload16(Aptr + (size_t)(Aoff + ar0) * 1024 + kk + aj0 * 8, As + c0 * 8);
    gload16(Aptr + (size_t)(Aoff + ar1) * 1024 + kk + aj1 * 8, As + c1 * 8);
    gload16(Bptr + (size_t)(Boff + ar0) * 1024 + kk + aj0 * 8, Bs + c0 * 8);
    gload16(Bptr + (size_t)(Boff + ar1) * 1024 + kk + aj1 * 8, Bs + c1 * 8);
    __syncthreads();
    bf16x8 af[4], bff[4];
#pragma unroll
    for (int mt = 0; mt < 4; ++mt)
      af[mt] = *(const bf16x8*)(As + (wm + mt * 16 + lm) * 32 + quad * 8);
#pragma unroll
    for (int nt = 0; nt < 4; ++nt)
      bff[nt] = *(const bf16x8*)(Bs + (wn + nt * 16 + lm) * 32 + quad * 8);
#pragma unroll
    for (int mt = 0; mt < 4; ++mt)
#pragma unroll
      for (int nt = 0; nt < 4; ++nt)
        acc[mt][nt] = __builtin_amdgcn_mfma_f32_16x16x32_bf16(
            af[mt], bff[nt], acc[mt][nt], 0, 0, 0);
    __syncthreads();
  }

  if (qkv < 2) {
    unsigned short* OUT = (qkv == 0) ? Qo : Ko;
    const float scale = (qkv == 0) ? 0.125f : 1.0f;
#pragma unroll
    for (int mt = 0; mt < 4; ++mt) {
      const int d = d0 + wm + mt * 16 + quad * 4;     // 4 consecutive d in regs
      const int g = d >> 8, hpg = (d >> 6) & 3, hd = d & 63;
      const float4 bb = *(const float4*)(bias + d);
#pragma unroll
      for (int nt = 0; nt < 4; ++nt) {
        const int srow = s0 + wn + nt * 16 + lm;
        const int bidx = srow >> 11, s = srow & 2047;
        const int head = (bidx * 4 + g) * 4 + hpg;
        ushort4 o;
        o.x = f2bf((acc[mt][nt][0] + bb.x) * scale);
        o.y = f2bf((acc[mt][nt][1] + bb.y) * scale);
        o.z = f2bf((acc[mt][nt][2] + bb.z) * scale);
        o.w = f2bf((acc[mt][nt][3] + bb.w) * scale);
        *(ushort4*)(OUT + (size_t)head * 131072 + (size_t)s * 64 + hd) = o;
      }
    }
  } else {
#pragma unroll
    for (int nt = 0; nt < 4; ++nt) {
      const int d = d0 + wn + nt * 16 + lm;
      const int g = d >> 8, hpg = (d >> 6) & 3, hd = d & 63;
      const float bb = bias[d];
#pragma unroll
      for (int mt = 0; mt < 4; ++mt) {
        const int sbase = s0 + wm + mt * 16 + quad * 4;  // 4 consecutive s in regs
        const int bidx = sbase >> 11, s = sbase & 2047;
        const int head = (bidx * 4 + g) * 4 + hpg;
        ushort4 o;
        o.x = f2bf(acc[mt][nt][0] + bb);
        o.y = f2bf(acc[mt][nt][1] + bb);
        o.z = f2bf(acc[mt][nt][2] + bb);
        o.w = f2bf(acc[mt][nt][3] + bb);
        *(ushort4*)(VTo + (size_t)head * 131072 + (size_t)hd * 2048 + s) = o;
      }
    }
  }
}

// ---- double-buffered K/V staging with 16B-granular XOR swizzle ----
static __device__ __forceinline__ void stage_kv(
    const unsigned short* Kh, const unsigned short* Vh, int kv0,
    unsigned short* ksl, unsigned short* vsl, int tid) {
#pragma unroll
  for (int t = 0; t < 4; ++t) {
    int i = t * 256 + tid;
    int slab = i >> 9, kv = (i >> 2) & 127, tp = i & 3;
    int tc = tp ^ ((kv >> 1) & 3);
    gload16(Kh + (size_t)(kv0 + kv) * 64 + slab * 32 + tc * 8, ksl + (size_t)i * 8);
  }
#pragma unroll
  for (int t = 0; t < 4; ++t) {
    int i = t * 256 + tid;
    int hd = i >> 4, tp = i & 15;
    int tc = tp ^ ((hd >> 1) & 7);
    gload16(Vh + (size_t)hd * 2048 + kv0 + tc * 8, vsl + (size_t)i * 8);
  }
}

// ---------------- attention (unchanged from R2) ----------------
__launch_bounds__(256, 2)
__global__ void attn_kernel(const unsigned short* __restrict__ Q,
                            const unsigned short* __restrict__ K,
                            const unsigned short* __restrict__ VT,
                            unsigned short* __restrict__ ctx) {
  __shared__ unsigned short Ks[2][8192];
  __shared__ unsigned short Vs[2][8192];

  const int head = blockIdx.y;
  const int q0 = blockIdx.x * 128;
  const int b = head >> 4;
  const int colbase = (head & 15) * 64;

  const unsigned short* Kh = K + (size_t)head * 131072;
  const unsigned short* Vh = VT + (size_t)head * 131072;

  const int tid = threadIdx.x;
  const int lane = tid & 63;
  const int w = tid >> 6;
  const int lm = lane & 15;
  const int quad = lane >> 4;

  bf16x8 qf[2][2];
#pragma unroll
  for (int nt = 0; nt < 2; ++nt) {
    const size_t qrow = (size_t)(q0 + w * 32 + nt * 16 + lm);
#pragma unroll
    for (int c = 0; c < 2; ++c)
      qf[c][nt] = *(const bf16x8*)(Q + (size_t)head * 131072 + qrow * 64 +
                                   c * 32 + quad * 8);
  }

  stage_kv(Kh, Vh, 0, Ks[0], Vs[0], tid);
  __syncthreads();

  float psum[2] = {0.f, 0.f};
  f32x4 oacc[4][2] = {};
  const int kchunk = (quad ^ ((lm >> 1) & 3)) * 8;

  for (int it = 0; it < 16; ++it) {
    const int buf = it & 1;
    if (it < 15)
      stage_kv(Kh, Vh, (it + 1) * 128, Ks[buf ^ 1], Vs[buf ^ 1], tid);

    const unsigned short* kb = Ks[buf];
    const unsigned short* vb = Vs[buf];

#pragma unroll
    for (int mt = 0; mt < 8; ++mt) {
      f32x4 s0 = {}, s1 = {};
#pragma unroll
      for (int c = 0; c < 2; ++c) {
        bf16x8 kf = *(const bf16x8*)(kb + c * 4096 + (mt * 16 + lm) * 32 + kchunk);
        s0 = __builtin_amdgcn_mfma_f32_16x16x32_bf16(kf, qf[c][0], s0, 0, 0, 0);
        s1 = __builtin_amdgcn_mfma_f32_16x16x32_bf16(kf, qf[c][1], s1, 0, 0, 0);
      }
      bf16x4 pf[2];
#pragma unroll
      for (int nt = 0; nt < 2; ++nt) {
        const f32x4 s = nt ? s1 : s0;
        float e0 = expfast(s[0]), e1 = expfast(s[1]);
        float e2 = expfast(s[2]), e3 = expfast(s[3]);
        psum[nt] += (e0 + e1) + (e2 + e3);
        bf16x4 t;
        t[0] = (__bf16)e0; t[1] = (__bf16)e1; t[2] = (__bf16)e2; t[3] = (__bf16)e3;
        pf[nt] = t;
      }
#pragma unroll
      for (int hm = 0; hm < 4; ++hm) {
        bf16x4 vf = *(const bf16x4*)(vb + (hm * 16 + lm) * 128 +
                                     (((mt * 4 + quad) ^ (lm & 14)) * 4));
        oacc[hm][0] = mfma16(vf, pf[0], oacc[hm][0]);
        oacc[hm][1] = mfma16(vf, pf[1], oacc[hm][1]);
      }
    }
    __syncthreads();
  }

#if MFMA16_FALLBACK
  asm volatile("s_nop 7\n\ts_nop 7");
#endif
#pragma unroll
  for (int nt = 0; nt < 2; ++nt) {
    float p = psum[nt];
    p += __shfl_xor(p, 16, 64);
    p += __shfl_xor(p, 32, 64);
    const float inv = 1.0f / p;
    const size_t row = (size_t)(b * 2048 + q0 + w * 32 + nt * 16 + lm);
#pragma unroll
    for (int hm = 0; hm < 4; ++hm) {
      ushort4 o;
      o.x = f2bf(oacc[hm][nt][0] * inv);
      o.y = f2bf(oacc[hm][nt][1] * inv);
      o.z = f2bf(oacc[hm][nt][2] * inv);
      o.w = f2bf(oacc[hm][nt][3] * inv);
      *(ushort4*)(ctx + row * 1024 + colbase + hm * 16 + quad * 4) = o;
    }
  }
}

// ---------------- output projection: C^T = Wo·ctx^T, float4 stores ----------
__launch_bounds__(256, 2)
__global__ void out_gemm(const unsigned short* __restrict__ A,   // ctx [4096][1024]
                         const unsigned short* __restrict__ Wb,  // Wo   [1024][1024]
                         const float* __restrict__ bo,
                         float* __restrict__ out) {
  __shared__ unsigned short As[128 * 32];   // Wo rows (o-dim)
  __shared__ unsigned short Bs[128 * 32];   // ctx rows (s-dim)
  const int s0 = blockIdx.x * 128;
  const int o0 = blockIdx.y * 128;

  const int tid = threadIdx.x;
  const int lane = tid & 63;
  const int wid = tid >> 6;
  const int wm = (wid >> 1) * 64;
  const int wn = (wid & 1) * 64;
  const int lm = lane & 15;
  const int quad = lane >> 4;

  const int c0 = tid, c1 = 256 + tid;
  const int ar0 = c0 >> 2, aj0 = c0 & 3;
  const int ar1 = c1 >> 2, aj1 = c1 & 3;

  f32x4 acc[4][4] = {};

  for (int kk = 0; kk < 1024; kk += 32) {
    gload16(Wb + (size_t)(o0 + ar0) * 1024 + kk + aj0 * 8, As + c0 * 8);
    gload16(Wb + (size_t)(o0 + ar1) * 1024 + kk + aj1 * 8, As + c1 * 8);
    gload16(A + (size_t)(s0 + ar0) * 1024 + kk + aj0 * 8, Bs + c0 * 8);
    gload16(A + (size_t)(s0 + ar1) * 1024 + kk + aj1 * 8, Bs + c1 * 8);
    __syncthreads();
    bf16x8 af[4], bff[4];
#pragma unroll
    for (int mt = 0; mt < 4; ++mt)
      af[mt] = *(const bf16x8*)(As + (wm + mt * 16 + lm) * 32 + quad * 8);
#pragma unroll
    for (int nt = 0; nt < 4; ++nt)
      bff[nt] = *(const bf16x8*)(Bs + (wn + nt * 16 + lm) * 32 + quad * 8);
#pragma unroll
    for (int mt = 0; mt < 4; ++mt)
#pragma unroll
      for (int nt = 0; nt < 4; ++nt)
        acc[mt][nt] = __builtin_amdgcn_mfma_f32_16x16x32_bf16(
            af[mt], bff[nt], acc[mt][nt], 0, 0, 0);
    __syncthreads();
  }

#pragma unroll
  for (int mt = 0; mt < 4; ++mt) {
    const int o = o0 + wm + mt * 16 + quad * 4;       // 4 consecutive o in regs
    const float4 bb = *(const float4*)(bo + o);
#pragma unroll
    for (int nt = 0; nt < 4; ++nt) {
      const int s = s0 + wn + nt * 16 + lm;
      float4 v;
      v.x = acc[mt][nt][0] + bb.x;
      v.y = acc[mt][nt][1] + bb.y;
      v.z = acc[mt][nt][2] + bb.z;
      v.w = acc[mt][nt][3] + bb.w;
      *(float4*)(out + (size_t)s * 1024 + o) = v;
    }
  }
}

extern "C" void kernel_launch(void* const* d_in, const int* in_sizes, int n_in,
                              void* d_out, int out_size, void* d_ws, size_t ws_size,
                              hipStream_t stream) {
  const float* x  = (const float*)d_in[0];
  const float* Wq = (const float*)d_in[1];
  const float* bq = (const float*)d_in[2];
  const float* Wk = (const float*)d_in[3];
  const float* bk = (const float*)d_in[4];
  const float* Wv = (const float*)d_in[5];
  const float* bv = (const float*)d_in[6];
  const float* Wo = (const float*)d_in[7];
  const float* bo = (const float*)d_in[8];
  float* out = (float*)d_out;

  char* ws = (char*)d_ws;
  unsigned short* xb  = (unsigned short*)(ws + 0);          //  8 MB
  unsigned short* wqb = (unsigned short*)(ws + 8388608);    //  2 MB
  unsigned short* wkb = (unsigned short*)(ws + 10485760);   //  2 MB
  unsigned short* wvb = (unsigned short*)(ws + 12582912);   //  2 MB
  unsigned short* wob = (unsigned short*)(ws + 14680064);   //  2 MB
  unsigned short* Qb  = (unsigned short*)(ws + 16777216);   //  8 MB [32][2048][64]
  unsigned short* Kb  = (unsigned short*)(ws + 25165824);   //  8 MB [32][2048][64]
  unsigned short* VTb = (unsigned short*)(ws + 33554432);   //  8 MB [32][64][2048]
  unsigned short* ctxb= (unsigned short*)(ws + 41943040);   //  8 MB [4096][1024]
  if (ws_size < 50331648) return;

  cvt_all<<<8192, 256, 0, stream>>>(x, Wq, Wk, Wv, Wo, (ushort4*)ws);
  qkv_gemm<<<dim3(32, 24), 256, 0, stream>>>(xb, wqb, wkb, wvb, bq, bk, bv,
                                             Qb, Kb, VTb);
  attn_kernel<<<dim3(16, 32), 256, 0, stream>>>(Qb, Kb, VTb, ctxb);
  out_gemm<<<dim3(32, 8), 256, 0, stream>>>(ctxb, wob, bo, out);
}